// Round 3
// baseline (244.950 us; speedup 1.0000x reference)
//
#include <hip/hip_runtime.h>
#include <hip/hip_bf16.h>
#include <math.h>

// BayesPredictor: inputs [B,D] f32, alphas [B] f32, data [N,D] f32
#define BB 32
#define DD 128
#define NN 32768

#define NB 512              // kernel-1 blocks
#define THREADS 512         // 8 waves
#define ROWS_PB (NN/NB)     // 64 rows per block
#define TILE 32             // rows per LDS tile
#define NT (ROWS_PB/TILE)   // 2 tiles per block
#define HW 17               // half-row width in float4 (16 data + 1 pad -> disjoint banks per h)
#define TILE_F4 (TILE*2*HW) // 1088 float4 per tile buffer
#define WS_STRIDE 132       // floats per (block,b) partial: m, s, pad, pad, acc[128]
#define REGION (BB*WS_STRIDE) // 4224 floats per merge region

// ---------------- kernel 1: streaming pass over data, per-block online softmax ----------------
__global__ __launch_bounds__(THREADS, 4) void bayes_k1(
    const float* __restrict__ inputs, const float* __restrict__ alphas,
    const float* __restrict__ data, float* __restrict__ ws)
{
    __shared__ float4 buf[2][TILE_F4];   // 2 * 1088 * 16B = 34816 B

    const int tid  = threadIdx.x;
    const int lane = tid & 63;
    const int wv   = tid >> 6;        // wave 0..7
    const int b    = lane >> 1;       // batch handled by this lane-pair
    const int h    = lane & 1;        // which 64-float half of D
    const int bid  = blockIdx.x;

    // per-b constants
    const float alpha = alphas[b];
    const float sa    = sqrtf(alpha);
    const float var   = 1.0f - alpha;
    const float c1    = sa / var;
    const float c2    = 0.5f * alpha / var;

    // inputs half-row -> registers (64 floats)
    float4 in4[16];
    {
        const float4* ig = (const float4*)(inputs + b * DD + h * 64);
        #pragma unroll
        for (int j = 0; j < 16; ++j) in4[j] = ig[j];
    }

    // online softmax state (deferred max, threshold 10)
    float m = -INFINITY, s = 0.0f;
    float4 acc[16];
    #pragma unroll
    for (int j = 0; j < 16; ++j) acc[j] = make_float4(0.f, 0.f, 0.f, 0.f);

    const float4* g4 = (const float4*)(data) + (size_t)bid * (ROWS_PB * DD / 4);

    // prologue: stage tile 0 (1024 f4; 2 per thread). LDS layout: half-row hr=(row*2+h), width 17 f4
    {
        float4 r0[2];
        #pragma unroll
        for (int k = 0; k < 2; ++k) r0[k] = g4[k * THREADS + tid];
        #pragma unroll
        for (int k = 0; k < 2; ++k) {
            const int f  = k * THREADS + tid;          // tile f4 index (32 f4 per row)
            const int rt = f >> 5, c = f & 31;
            buf[0][(rt * 2 + (c >> 4)) * HW + (c & 15)] = r0[k];
        }
    }
    __syncthreads();

    for (int t = 0; t < NT; ++t) {
        const int cur = t & 1;

        // T14 async-split: issue next tile's global loads now, LDS-write after compute
        float4 rs[2];
        if (t + 1 < NT) {
            #pragma unroll
            for (int k = 0; k < 2; ++k) rs[k] = g4[(t + 1) * 1024 + k * THREADS + tid];
        }

        // row norms: wave w owns tile rows w*4..w*4+3 = half-rows w*8..w*8+7
        // 8 lanes per half-row, 2 f4 each
        const int hrow = wv * 8 + (lane >> 3);
        const int p    = lane & 7;
        float nn = 0.0f;
        #pragma unroll
        for (int j = 0; j < 2; ++j) {
            const float4 d = buf[cur][hrow * HW + p * 2 + j];
            nn = fmaf(d.x, d.x, nn); nn = fmaf(d.y, d.y, nn);
            nn = fmaf(d.z, d.z, nn); nn = fmaf(d.w, d.w, nn);
        }
        nn += __shfl_xor(nn, 1);
        nn += __shfl_xor(nn, 2);
        nn += __shfl_xor(nn, 4);   // half-row sums
        nn += __shfl_xor(nn, 8);   // combine the two halves -> full row norm on 16-lane group

        // process the wave's 4 rows
        #pragma unroll
        for (int i = 0; i < 4; ++i) {
            const float4* rb = &buf[cur][((wv * 4 + i) * 2 + h) * HW];

            float4 dot4 = make_float4(0.f, 0.f, 0.f, 0.f);
            #pragma unroll
            for (int j = 0; j < 16; ++j) {
                const float4 d4 = rb[j];
                dot4.x = fmaf(in4[j].x, d4.x, dot4.x);
                dot4.y = fmaf(in4[j].y, d4.y, dot4.y);
                dot4.z = fmaf(in4[j].z, d4.z, dot4.z);
                dot4.w = fmaf(in4[j].w, d4.w, dot4.w);
            }
            float dot = (dot4.x + dot4.y) + (dot4.z + dot4.w);
            dot += __shfl_xor(dot, 1);          // combine halves -> full dot on both lanes

            const float nr = __shfl(nn, i << 4);
            const float logit = c1 * dot - c2 * nr;

            float pp = logit - m;
            if (pp > 10.0f) {                   // deferred rescale (rare)
                const float sc = __expf(-pp);   // first row: exp(-inf)=0
                s *= sc;
                #pragma unroll
                for (int j = 0; j < 16; ++j) {
                    acc[j].x *= sc; acc[j].y *= sc; acc[j].z *= sc; acc[j].w *= sc;
                }
                m = logit; pp = 0.0f;
            }
            const float wgt = __expf(pp);
            s += wgt;
            #pragma unroll
            for (int j = 0; j < 16; ++j) {
                const float4 d = rb[j];
                acc[j].x = fmaf(wgt, d.x, acc[j].x);
                acc[j].y = fmaf(wgt, d.y, acc[j].y);
                acc[j].z = fmaf(wgt, d.z, acc[j].z);
                acc[j].w = fmaf(wgt, d.w, acc[j].w);
            }
        }

        // write next tile to the other buffer (vmcnt stall lands AFTER compute)
        if (t + 1 < NT) {
            #pragma unroll
            for (int k = 0; k < 2; ++k) {
                const int f  = k * THREADS + tid;
                const int rt = f >> 5, c = f & 31;
                buf[cur ^ 1][(rt * 2 + (c >> 4)) * HW + (c & 15)] = rs[k];
            }
        }
        __syncthreads();
    }

    // ---------------- epilogue: 8-wave pair-merge tree via 2 LDS regions ----------------
    float* red = (float*)&buf[0][0];   // 2 regions x 4224 floats (fits in 8704)

    auto publish = [&](int R) {
        float* regp = red + R * REGION + b * WS_STRIDE;
        if (h == 0) { regp[0] = m; regp[1] = s; }
        float4* ra = (float4*)(regp + 4) + h * 16;
        #pragma unroll
        for (int j = 0; j < 16; ++j) ra[j] = acc[j];
    };
    auto domerge = [&](int R) {
        const float* regp = red + R * REGION + b * WS_STRIDE;
        const float mo = regp[0], so = regp[1];
        const float M  = fmaxf(m, mo);
        const float e0 = __expf(m - M), e1 = __expf(mo - M);
        s = s * e0 + so * e1;
        const float4* ra = (const float4*)(regp + 4) + h * 16;
        #pragma unroll
        for (int j = 0; j < 16; ++j) {
            const float4 d = ra[j];
            acc[j].x = acc[j].x * e0 + e1 * d.x;
            acc[j].y = acc[j].y * e0 + e1 * d.y;
            acc[j].z = acc[j].z * e0 + e1 * d.z;
            acc[j].w = acc[j].w * e0 + e1 * d.w;
        }
        m = M;
    };

    // pairs (0,4),(1,5) then (2,6),(3,7) then (0,2),(1,3) then (0,1)
    if (wv == 4) publish(0);
    if (wv == 5) publish(1);
    __syncthreads();
    if (wv == 0) domerge(0);
    if (wv == 1) domerge(1);
    __syncthreads();
    if (wv == 6) publish(0);
    if (wv == 7) publish(1);
    __syncthreads();
    if (wv == 2) domerge(0);
    if (wv == 3) domerge(1);
    __syncthreads();
    if (wv == 2) publish(0);
    if (wv == 3) publish(1);
    __syncthreads();
    if (wv == 0) domerge(0);
    if (wv == 1) domerge(1);
    __syncthreads();
    if (wv == 1) publish(0);
    __syncthreads();
    if (wv == 0) {
        domerge(0);
        float* wsp = ws + ((size_t)bid * BB + b) * WS_STRIDE;
        if (h == 0) { wsp[0] = m; wsp[1] = s; }
        float4* wa = (float4*)(wsp + 4) + h * 16;
        #pragma unroll
        for (int j = 0; j < 16; ++j) wa[j] = acc[j];
    }
}

// ---------------- kernel 2: cross-block softmax combine + output ----------------
#define NPART NB   // 512 partials per b

__global__ __launch_bounds__(256) void bayes_k2(
    const float* __restrict__ inputs, const float* __restrict__ alphas,
    const float* __restrict__ ws, float* __restrict__ out)
{
    const int b  = blockIdx.x >> 2;   // 0..31
    const int dq = blockIdx.x & 3;    // d-quarter
    const int tid = threadIdx.x;

    __shared__ float e_s[NPART];
    __shared__ float red_s[16];
    __shared__ float part[8][32];

    // per-partial m,s: 512 partials, 2 per thread
    const float* base = ws + (size_t)b * WS_STRIDE;
    float mi[2], si[2];
    #pragma unroll
    for (int q = 0; q < 2; ++q) {
        const int i = tid + q * 256;
        mi[q] = base[(size_t)i * (BB * WS_STRIDE)];
        si[q] = base[(size_t)i * (BB * WS_STRIDE) + 1];
    }

    // global max M over 512 partials
    float mm = fmaxf(mi[0], mi[1]);
    #pragma unroll
    for (int off = 1; off <= 32; off <<= 1) mm = fmaxf(mm, __shfl_xor(mm, off));
    if ((tid & 63) == 0) red_s[tid >> 6] = mm;
    __syncthreads();
    const float M = fmaxf(fmaxf(red_s[0], red_s[1]), fmaxf(red_s[2], red_s[3]));

    float ss = 0.0f;
    #pragma unroll
    for (int q = 0; q < 2; ++q) {
        const float ei = __expf(mi[q] - M);
        e_s[tid + q * 256] = ei;
        ss = fmaf(si[q], ei, ss);
    }
    #pragma unroll
    for (int off = 1; off <= 32; off <<= 1) ss += __shfl_xor(ss, off);
    if ((tid & 63) == 0) red_s[8 + (tid >> 6)] = ss;
    __syncthreads();
    const float S = (red_s[8] + red_s[9]) + (red_s[10] + red_s[11]);

    // x0 slice: 32 d-values, 8-way split over partials (64 each)
    const int dd = tid & 31, ii = tid >> 5;
    const int d  = dq * 32 + dd;
    float x = 0.0f;
    #pragma unroll 8
    for (int k = 0; k < 64; ++k) {
        const int i = ii + k * 8;
        x = fmaf(e_s[i], ws[((size_t)i * BB + b) * WS_STRIDE + 4 + d], x);
    }
    part[ii][dd] = x;
    __syncthreads();

    if (tid < 32) {
        float x0 = 0.0f;
        #pragma unroll
        for (int q = 0; q < 8; ++q) x0 += part[q][tid];
        x0 /= S;
        const float alpha = alphas[b];
        const float sa  = sqrtf(alpha);
        const float var = 1.0f - alpha;
        const int dout  = dq * 32 + tid;
        out[b * DD + dout] = (inputs[b * DD + dout] - sa * x0) / sqrtf(var);
    }
}

extern "C" void kernel_launch(void* const* d_in, const int* in_sizes, int n_in,
                              void* d_out, int out_size, void* d_ws, size_t ws_size,
                              hipStream_t stream)
{
    const float* inputs = (const float*)d_in[0];   // [B,D]
    const float* alphas = (const float*)d_in[1];   // [B]
    const float* data   = (const float*)d_in[2];   // [N,D]
    float* out = (float*)d_out;
    float* ws  = (float*)d_ws;                     // needs NB*BB*132*4 = 8.65 MB

    bayes_k1<<<NB, THREADS, 0, stream>>>(inputs, alphas, data, ws);
    bayes_k2<<<BB * 4, 256, 0, stream>>>(inputs, alphas, ws, out);
}

// Round 4
// 103.450 us; speedup vs baseline: 2.3678x; 2.3678x over previous
//
#include <hip/hip_runtime.h>
#include <hip/hip_bf16.h>
#include <math.h>

// BayesPredictor: inputs [B,D] f32, alphas [B] f32, data [N,D] f32
#define BB 32
#define DD 128
#define NN 32768

#define NB 512              // kernel-1 blocks
#define THREADS 512         // 8 waves
#define ROWS_PB (NN/NB)     // 64 rows per block
#define TILE 32             // rows per LDS tile
#define NT (ROWS_PB/TILE)   // 2 tiles per block
#define HW 17               // half-row width in float4 (16 data + 1 pad -> disjoint banks per h)
#define TILE_F4 (TILE*2*HW) // 1088 float4 per tile buffer
#define WS_STRIDE 132       // floats per (block,b) partial: m, s, pad, pad, acc[128]
#define REGION (BB*WS_STRIDE) // 4224 floats per merge region

// ---------------- kernel 1: streaming pass over data, per-block online softmax ----------------
// NOTE: occupancy is controlled by grid geometry ONLY. __launch_bounds__(512,4) made the
// allocator target 64 VGPR -> spilled the 128-VGPR accumulator state to scratch
// (409MB fetch/dispatch, 3.6x slowdown). Plain (512) compiles this body to ~128 VGPR.
__global__ __launch_bounds__(THREADS) void bayes_k1(
    const float* __restrict__ inputs, const float* __restrict__ alphas,
    const float* __restrict__ data, float* __restrict__ ws)
{
    __shared__ float4 buf[2][TILE_F4];   // 2 * 1088 * 16B = 34816 B

    const int tid  = threadIdx.x;
    const int lane = tid & 63;
    const int wv   = tid >> 6;        // wave 0..7
    const int b    = lane >> 1;       // batch handled by this lane-pair
    const int h    = lane & 1;        // which 64-float half of D
    const int bid  = blockIdx.x;

    // per-b constants
    const float alpha = alphas[b];
    const float sa    = sqrtf(alpha);
    const float var   = 1.0f - alpha;
    const float c1    = sa / var;
    const float c2    = 0.5f * alpha / var;

    // inputs half-row -> registers (64 floats)
    float4 in4[16];
    {
        const float4* ig = (const float4*)(inputs + b * DD + h * 64);
        #pragma unroll
        for (int j = 0; j < 16; ++j) in4[j] = ig[j];
    }

    // online softmax state (deferred max, threshold 10)
    float m = -INFINITY, s = 0.0f;
    float4 acc[16];
    #pragma unroll
    for (int j = 0; j < 16; ++j) acc[j] = make_float4(0.f, 0.f, 0.f, 0.f);

    const float4* g4 = (const float4*)(data) + (size_t)bid * (ROWS_PB * DD / 4);

    // prologue: stage tile 0 (1024 f4; 2 per thread). LDS layout: half-row hr=(row*2+h), width 17 f4
    {
        float4 r0[2];
        #pragma unroll
        for (int k = 0; k < 2; ++k) r0[k] = g4[k * THREADS + tid];
        #pragma unroll
        for (int k = 0; k < 2; ++k) {
            const int f  = k * THREADS + tid;          // tile f4 index (32 f4 per row)
            const int rt = f >> 5, c = f & 31;
            buf[0][(rt * 2 + (c >> 4)) * HW + (c & 15)] = r0[k];
        }
    }
    __syncthreads();

    for (int t = 0; t < NT; ++t) {
        const int cur = t & 1;

        // T14 async-split: issue next tile's global loads now, LDS-write after compute
        float4 rs[2];
        if (t + 1 < NT) {
            #pragma unroll
            for (int k = 0; k < 2; ++k) rs[k] = g4[(t + 1) * 1024 + k * THREADS + tid];
        }

        // row norms: wave w owns tile rows w*4..w*4+3 = half-rows w*8..w*8+7
        // 8 lanes per half-row, 2 f4 each
        const int hrow = wv * 8 + (lane >> 3);
        const int p    = lane & 7;
        float nn = 0.0f;
        #pragma unroll
        for (int j = 0; j < 2; ++j) {
            const float4 d = buf[cur][hrow * HW + p * 2 + j];
            nn = fmaf(d.x, d.x, nn); nn = fmaf(d.y, d.y, nn);
            nn = fmaf(d.z, d.z, nn); nn = fmaf(d.w, d.w, nn);
        }
        nn += __shfl_xor(nn, 1);
        nn += __shfl_xor(nn, 2);
        nn += __shfl_xor(nn, 4);   // half-row sums
        nn += __shfl_xor(nn, 8);   // combine the two halves -> full row norm on 16-lane group

        // process the wave's 4 rows
        #pragma unroll
        for (int i = 0; i < 4; ++i) {
            const float4* rb = &buf[cur][((wv * 4 + i) * 2 + h) * HW];

            float4 dot4 = make_float4(0.f, 0.f, 0.f, 0.f);
            #pragma unroll
            for (int j = 0; j < 16; ++j) {
                const float4 d4 = rb[j];
                dot4.x = fmaf(in4[j].x, d4.x, dot4.x);
                dot4.y = fmaf(in4[j].y, d4.y, dot4.y);
                dot4.z = fmaf(in4[j].z, d4.z, dot4.z);
                dot4.w = fmaf(in4[j].w, d4.w, dot4.w);
            }
            float dot = (dot4.x + dot4.y) + (dot4.z + dot4.w);
            dot += __shfl_xor(dot, 1);          // combine halves -> full dot on both lanes

            const float nr = __shfl(nn, i << 4);
            const float logit = c1 * dot - c2 * nr;

            float pp = logit - m;
            if (pp > 10.0f) {                   // deferred rescale (rare)
                const float sc = __expf(-pp);   // first row: exp(-inf)=0
                s *= sc;
                #pragma unroll
                for (int j = 0; j < 16; ++j) {
                    acc[j].x *= sc; acc[j].y *= sc; acc[j].z *= sc; acc[j].w *= sc;
                }
                m = logit; pp = 0.0f;
            }
            const float wgt = __expf(pp);
            s += wgt;
            #pragma unroll
            for (int j = 0; j < 16; ++j) {
                const float4 d = rb[j];
                acc[j].x = fmaf(wgt, d.x, acc[j].x);
                acc[j].y = fmaf(wgt, d.y, acc[j].y);
                acc[j].z = fmaf(wgt, d.z, acc[j].z);
                acc[j].w = fmaf(wgt, d.w, acc[j].w);
            }
        }

        // write next tile to the other buffer (vmcnt stall lands AFTER compute)
        if (t + 1 < NT) {
            #pragma unroll
            for (int k = 0; k < 2; ++k) {
                const int f  = k * THREADS + tid;
                const int rt = f >> 5, c = f & 31;
                buf[cur ^ 1][(rt * 2 + (c >> 4)) * HW + (c & 15)] = rs[k];
            }
        }
        __syncthreads();
    }

    // ---------------- epilogue: 8-wave pair-merge tree via 2 LDS regions ----------------
    float* red = (float*)&buf[0][0];   // 2 regions x 4224 floats (fits in 8704)

    auto publish = [&](int R) {
        float* regp = red + R * REGION + b * WS_STRIDE;
        if (h == 0) { regp[0] = m; regp[1] = s; }
        float4* ra = (float4*)(regp + 4) + h * 16;
        #pragma unroll
        for (int j = 0; j < 16; ++j) ra[j] = acc[j];
    };
    auto domerge = [&](int R) {
        const float* regp = red + R * REGION + b * WS_STRIDE;
        const float mo = regp[0], so = regp[1];
        const float M  = fmaxf(m, mo);
        const float e0 = __expf(m - M), e1 = __expf(mo - M);
        s = s * e0 + so * e1;
        const float4* ra = (const float4*)(regp + 4) + h * 16;
        #pragma unroll
        for (int j = 0; j < 16; ++j) {
            const float4 d = ra[j];
            acc[j].x = acc[j].x * e0 + e1 * d.x;
            acc[j].y = acc[j].y * e0 + e1 * d.y;
            acc[j].z = acc[j].z * e0 + e1 * d.z;
            acc[j].w = acc[j].w * e0 + e1 * d.w;
        }
        m = M;
    };

    // pairs (0,4),(1,5) then (2,6),(3,7) then (0,2),(1,3) then (0,1)
    if (wv == 4) publish(0);
    if (wv == 5) publish(1);
    __syncthreads();
    if (wv == 0) domerge(0);
    if (wv == 1) domerge(1);
    __syncthreads();
    if (wv == 6) publish(0);
    if (wv == 7) publish(1);
    __syncthreads();
    if (wv == 2) domerge(0);
    if (wv == 3) domerge(1);
    __syncthreads();
    if (wv == 2) publish(0);
    if (wv == 3) publish(1);
    __syncthreads();
    if (wv == 0) domerge(0);
    if (wv == 1) domerge(1);
    __syncthreads();
    if (wv == 1) publish(0);
    __syncthreads();
    if (wv == 0) {
        domerge(0);
        float* wsp = ws + ((size_t)bid * BB + b) * WS_STRIDE;
        if (h == 0) { wsp[0] = m; wsp[1] = s; }
        float4* wa = (float4*)(wsp + 4) + h * 16;
        #pragma unroll
        for (int j = 0; j < 16; ++j) wa[j] = acc[j];
    }
}

// ---------------- kernel 2: cross-block softmax combine + output ----------------
#define NPART NB   // 512 partials per b

__global__ __launch_bounds__(256) void bayes_k2(
    const float* __restrict__ inputs, const float* __restrict__ alphas,
    const float* __restrict__ ws, float* __restrict__ out)
{
    const int b  = blockIdx.x >> 2;   // 0..31
    const int dq = blockIdx.x & 3;    // d-quarter
    const int tid = threadIdx.x;

    __shared__ float e_s[NPART];
    __shared__ float red_s[16];
    __shared__ float part[8][32];

    // per-partial m,s: 512 partials, 2 per thread
    const float* base = ws + (size_t)b * WS_STRIDE;
    float mi[2], si[2];
    #pragma unroll
    for (int q = 0; q < 2; ++q) {
        const int i = tid + q * 256;
        mi[q] = base[(size_t)i * (BB * WS_STRIDE)];
        si[q] = base[(size_t)i * (BB * WS_STRIDE) + 1];
    }

    // global max M over 512 partials
    float mm = fmaxf(mi[0], mi[1]);
    #pragma unroll
    for (int off = 1; off <= 32; off <<= 1) mm = fmaxf(mm, __shfl_xor(mm, off));
    if ((tid & 63) == 0) red_s[tid >> 6] = mm;
    __syncthreads();
    const float M = fmaxf(fmaxf(red_s[0], red_s[1]), fmaxf(red_s[2], red_s[3]));

    float ss = 0.0f;
    #pragma unroll
    for (int q = 0; q < 2; ++q) {
        const float ei = __expf(mi[q] - M);
        e_s[tid + q * 256] = ei;
        ss = fmaf(si[q], ei, ss);
    }
    #pragma unroll
    for (int off = 1; off <= 32; off <<= 1) ss += __shfl_xor(ss, off);
    if ((tid & 63) == 0) red_s[8 + (tid >> 6)] = ss;
    __syncthreads();
    const float S = (red_s[8] + red_s[9]) + (red_s[10] + red_s[11]);

    // x0 slice: 32 d-values, 8-way split over partials (64 each)
    const int dd = tid & 31, ii = tid >> 5;
    const int d  = dq * 32 + dd;
    float x = 0.0f;
    #pragma unroll 8
    for (int k = 0; k < 64; ++k) {
        const int i = ii + k * 8;
        x = fmaf(e_s[i], ws[((size_t)i * BB + b) * WS_STRIDE + 4 + d], x);
    }
    part[ii][dd] = x;
    __syncthreads();

    if (tid < 32) {
        float x0 = 0.0f;
        #pragma unroll
        for (int q = 0; q < 8; ++q) x0 += part[q][tid];
        x0 /= S;
        const float alpha = alphas[b];
        const float sa  = sqrtf(alpha);
        const float var = 1.0f - alpha;
        const int dout  = dq * 32 + tid;
        out[b * DD + dout] = (inputs[b * DD + dout] - sa * x0) / sqrtf(var);
    }
}

extern "C" void kernel_launch(void* const* d_in, const int* in_sizes, int n_in,
                              void* d_out, int out_size, void* d_ws, size_t ws_size,
                              hipStream_t stream)
{
    const float* inputs = (const float*)d_in[0];   // [B,D]
    const float* alphas = (const float*)d_in[1];   // [B]
    const float* data   = (const float*)d_in[2];   // [N,D]
    float* out = (float*)d_out;
    float* ws  = (float*)d_ws;                     // needs NB*BB*132*4 = 8.65 MB

    bayes_k1<<<NB, THREADS, 0, stream>>>(inputs, alphas, data, ws);
    bayes_k2<<<BB * 4, 256, 0, stream>>>(inputs, alphas, ws, out);
}

// Round 5
// 97.169 us; speedup vs baseline: 2.5209x; 1.0646x over previous
//
#include <hip/hip_runtime.h>
#include <math.h>

// BayesPredictor: inputs [B,D] f32, alphas [B] f32, data [N,D] f32
#define BB 32
#define DD 128
#define NN 32768

#define NB1 1024            // k1 blocks
#define T1 256              // k1 threads = 4 waves
#define ROWS 32             // data rows per block (single 16KB tile, no dbuf)
#define WS_STRIDE 132       // floats per (block,b) partial: m, s, pad, pad, acc[128]
#define NP NB1              // partials per b for k2

// ---------------- kernel 1 ----------------
// Wave layout: wv = {half (b-half), wr (row-subset)}; lane = 16 b-groups x 4 quad lanes.
// Each lane owns 32 floats (8 f4 chunks c = 4j+q) of inputs/acc/row. Rows are read from
// LDS ONCE per (row, b-half) into registers and reused for the acc update (round-4 k1
// re-read them -> LDS-issue-bound). LDS cols XOR-swizzled by row to kill bank conflicts.
// NOTE: no min-waves launch_bounds arg — (512,4) previously forced 64 VGPR and spilled.
__global__ __launch_bounds__(T1) void bayes_k1(
    const float* __restrict__ inputs, const float* __restrict__ alphas,
    const float* __restrict__ data, float* __restrict__ ws)
{
    __shared__ float4 tile[ROWS * 32];   // 16 KB, [row][col'] with col' = col ^ ((row&7)<<2)
    __shared__ float  ms[2][16][2];

    const int tid  = threadIdx.x;
    const int lane = tid & 63;
    const int wv   = tid >> 6;        // 0..3
    const int half = wv >> 1;         // b-half: 0 -> b 0..15, 1 -> b 16..31
    const int wr   = wv & 1;          // row subset: rows wr*16 .. wr*16+15
    const int br   = lane >> 2;       // b within half
    const int q    = lane & 3;        // quad slice
    const int b    = half * 16 + br;
    const int bid  = blockIdx.x;

    const float alpha = alphas[b];
    const float sa    = sqrtf(alpha);
    const float var   = 1.0f - alpha;
    const float c1    = sa / var;
    const float c2    = 0.5f * alpha / var;

    // stage tile: 4 f4 per thread, coalesced global, swizzled LDS
    const float4* g4 = (const float4*)data + (size_t)bid * (ROWS * DD / 4);
    {
        float4 v[4];
        #pragma unroll
        for (int k = 0; k < 4; ++k) v[k] = g4[k * T1 + tid];
        #pragma unroll
        for (int k = 0; k < 4; ++k) {
            const int f = k * T1 + tid;
            const int r = f >> 5, c = f & 31;
            tile[r * 32 + (c ^ ((r & 7) << 2))] = v[k];
        }
    }

    // inputs slice: chunks c = 4j+q
    float4 in4[8];
    {
        const float4* ig = (const float4*)inputs + b * 32;
        #pragma unroll
        for (int j = 0; j < 8; ++j) in4[j] = ig[4 * j + q];
    }

    __syncthreads();

    // norm prepass: lane (r_loc = lane>>2, q) covers row wr*16 + r_loc
    float nn = 0.0f;
    {
        const int r = wr * 16 + (lane >> 2);
        const int sw = (r & 7) << 2;
        #pragma unroll
        for (int j = 0; j < 8; ++j) {
            const float4 d = tile[r * 32 + ((4 * j + q) ^ sw)];
            nn = fmaf(d.x, d.x, nn); nn = fmaf(d.y, d.y, nn);
            nn = fmaf(d.z, d.z, nn); nn = fmaf(d.w, d.w, nn);
        }
        nn += __shfl_xor(nn, 1);
        nn += __shfl_xor(nn, 2);    // full row norm on all 4 quad lanes
    }

    // online softmax state (deferred rescale, threshold 10)
    float m = -INFINITY, s = 0.0f;
    float4 acc[8];
    #pragma unroll
    for (int j = 0; j < 8; ++j) acc[j] = make_float4(0.f, 0.f, 0.f, 0.f);

    #pragma unroll 4
    for (int rl = 0; rl < 16; ++rl) {
        const int r  = wr * 16 + rl;
        const int sw = (r & 7) << 2;

        float4 d4[8];                      // row slice -> regs (read ONCE)
        #pragma unroll
        for (int j = 0; j < 8; ++j) d4[j] = tile[r * 32 + ((4 * j + q) ^ sw)];

        float4 dv = make_float4(0.f, 0.f, 0.f, 0.f);
        #pragma unroll
        for (int j = 0; j < 8; ++j) {
            dv.x = fmaf(in4[j].x, d4[j].x, dv.x);
            dv.y = fmaf(in4[j].y, d4[j].y, dv.y);
            dv.z = fmaf(in4[j].z, d4[j].z, dv.z);
            dv.w = fmaf(in4[j].w, d4[j].w, dv.w);
        }
        float dot = (dv.x + dv.y) + (dv.z + dv.w);
        dot += __shfl_xor(dot, 1);
        dot += __shfl_xor(dot, 2);         // full dot on all 4 quad lanes

        const float nr    = __shfl(nn, rl << 2);
        const float logit = c1 * dot - c2 * nr;

        float pp = logit - m;
        if (pp > 10.0f) {                  // rare rescale; first row: exp(-inf)=0
            const float sc = __expf(-pp);
            s *= sc;
            #pragma unroll
            for (int j = 0; j < 8; ++j) {
                acc[j].x *= sc; acc[j].y *= sc; acc[j].z *= sc; acc[j].w *= sc;
            }
            m = logit; pp = 0.0f;
        }
        const float wgt = __expf(pp);
        s += wgt;
        #pragma unroll
        for (int j = 0; j < 8; ++j) {      // reuse registers — no LDS re-read
            acc[j].x = fmaf(wgt, d4[j].x, acc[j].x);
            acc[j].y = fmaf(wgt, d4[j].y, acc[j].y);
            acc[j].z = fmaf(wgt, d4[j].z, acc[j].z);
            acc[j].w = fmaf(wgt, d4[j].w, acc[j].w);
        }
    }

    // merge wr=1 wave into wr=0 wave (same b's, disjoint rows), then write partial
    __syncthreads();                       // done reading tile
    float* red = (float*)tile;             // [2][16][128] floats
    if (wr == 1) {
        if (q == 0) { ms[half][br][0] = m; ms[half][br][1] = s; }
        float4* rp = (float4*)(red + half * 2048 + br * 128);
        const int sw = (br & 7) << 2;
        #pragma unroll
        for (int j = 0; j < 8; ++j) rp[(4 * j + q) ^ sw] = acc[j];
    }
    __syncthreads();
    if (wr == 0) {
        const float mo = ms[half][br][0], so = ms[half][br][1];
        const float M  = fmaxf(m, mo);
        const float e0 = __expf(m - M), e1 = __expf(mo - M);
        s = s * e0 + so * e1;
        const float4* rp = (const float4*)(red + half * 2048 + br * 128);
        const int sw = (br & 7) << 2;
        #pragma unroll
        for (int j = 0; j < 8; ++j) {
            const float4 d = rp[(4 * j + q) ^ sw];
            acc[j].x = acc[j].x * e0 + e1 * d.x;
            acc[j].y = acc[j].y * e0 + e1 * d.y;
            acc[j].z = acc[j].z * e0 + e1 * d.z;
            acc[j].w = acc[j].w * e0 + e1 * d.w;
        }
        m = M;

        float* wsp = ws + ((size_t)bid * BB + b) * WS_STRIDE;
        if (q == 0) { wsp[0] = m; wsp[1] = s; }
        float4* wa = (float4*)(wsp + 4);
        #pragma unroll
        for (int j = 0; j < 8; ++j) wa[4 * j + q] = acc[j];   // natural d-order
    }
}

// ---------------- kernel 2: cross-block softmax combine + output ----------------
__global__ __launch_bounds__(256) void bayes_k2(
    const float* __restrict__ inputs, const float* __restrict__ alphas,
    const float* __restrict__ ws, float* __restrict__ out)
{
    const int b   = blockIdx.x >> 2;   // 0..31
    const int dq  = blockIdx.x & 3;    // d-quarter
    const int tid = threadIdx.x;

    __shared__ float e_s[NP];          // 1024 scale factors
    __shared__ float red_s[16];
    __shared__ float part[8][32];

    // per-partial m,s: 1024 partials, 4 per thread
    float mi[4], si[4];
    #pragma unroll
    for (int k = 0; k < 4; ++k) {
        const int i = tid + k * 256;
        const size_t idx = ((size_t)i * BB + b) * WS_STRIDE;
        mi[k] = ws[idx];
        si[k] = ws[idx + 1];
    }

    float mm = fmaxf(fmaxf(mi[0], mi[1]), fmaxf(mi[2], mi[3]));
    #pragma unroll
    for (int off = 1; off <= 32; off <<= 1) mm = fmaxf(mm, __shfl_xor(mm, off));
    if ((tid & 63) == 0) red_s[tid >> 6] = mm;
    __syncthreads();
    const float M = fmaxf(fmaxf(red_s[0], red_s[1]), fmaxf(red_s[2], red_s[3]));

    float ss = 0.0f;
    #pragma unroll
    for (int k = 0; k < 4; ++k) {
        const float ei = __expf(mi[k] - M);
        e_s[tid + k * 256] = ei;
        ss = fmaf(si[k], ei, ss);
    }
    #pragma unroll
    for (int off = 1; off <= 32; off <<= 1) ss += __shfl_xor(ss, off);
    if ((tid & 63) == 0) red_s[8 + (tid >> 6)] = ss;
    __syncthreads();
    const float S = (red_s[8] + red_s[9]) + (red_s[10] + red_s[11]);

    // x0 slice: 32 d-values, 8-way split over 1024 partials (128 each)
    const int dd = tid & 31, ii = tid >> 5;
    const int d  = dq * 32 + dd;
    float x = 0.0f;
    #pragma unroll 8
    for (int k = 0; k < 128; ++k) {
        const int i = ii + k * 8;
        x = fmaf(e_s[i], ws[((size_t)i * BB + b) * WS_STRIDE + 4 + d], x);
    }
    part[ii][dd] = x;
    __syncthreads();

    if (tid < 32) {
        float x0 = 0.0f;
        #pragma unroll
        for (int p = 0; p < 8; ++p) x0 += part[p][tid];
        x0 /= S;
        const float alpha = alphas[b];
        const float sa  = sqrtf(alpha);
        const float var = 1.0f - alpha;
        const int dout  = dq * 32 + tid;
        out[b * DD + dout] = (inputs[b * DD + dout] - sa * x0) / sqrtf(var);
    }
}

extern "C" void kernel_launch(void* const* d_in, const int* in_sizes, int n_in,
                              void* d_out, int out_size, void* d_ws, size_t ws_size,
                              hipStream_t stream)
{
    const float* inputs = (const float*)d_in[0];   // [B,D]
    const float* alphas = (const float*)d_in[1];   // [B]
    const float* data   = (const float*)d_in[2];   // [N,D]
    float* out = (float*)d_out;
    float* ws  = (float*)d_ws;                     // uses NB1*BB*132*4 = 17.3 MB

    bayes_k1<<<NB1, T1, 0, stream>>>(inputs, alphas, data, ws);
    bayes_k2<<<BB * 4, 256, 0, stream>>>(inputs, alphas, ws, out);
}

// Round 6
// 83.284 us; speedup vs baseline: 2.9412x; 1.1667x over previous
//
#include <hip/hip_runtime.h>
#include <math.h>

// BayesPredictor: inputs [B,D] f32, alphas [B] f32, data [N,D] f32
#define BB 32
#define DD 128
#define NN 32768

#define NB 512              // k1 blocks
#define RPB 64              // data rows per block
#define WS_STRIDE 136       // f32 per (b, block) partial: m, s, pad, pad, acc[128], pad[4]
#define NP NB               // partials per b

typedef __attribute__((ext_vector_type(8))) short bf16x8;
typedef __attribute__((ext_vector_type(4))) float f32x4;

// ---- LDS arena (bytes). Swizzle: 16B-granule XOR ((row&7)<<4) on every tile.
#define O_RH   0            // rows hi  bf16 [64][128] pitch 256
#define O_RL   16384        // rows lo  bf16 [64][128] pitch 256
#define O_INH  32768        // inputs hi bf16 [32][128] pitch 256
#define O_INL  40960        // inputs lo
#define O_RT   49152        // rows^T hi bf16 [128][64] pitch 128
#define O_D1   65536        // GEMM1 k-partials: [ni(2)][mt(4)][b(16)] pitch 80, f32x4 per g
#define O_NRM  75776        // 64 row norms f32
#define O_PT   O_INH        // P^T bf16 [32 b][64 r] pitch 128 (overlays inh after GEMM1)
#define O_X0   O_RH         // x0 f32 [32 b][128 d] pitch 512 (overlays Rh after GEMM1)
#define ARENA  76032

__device__ __forceinline__ unsigned bf16_rne(float x) {
    unsigned u = __builtin_bit_cast(unsigned, x);
    return (u + 0x7FFFu + ((u >> 16) & 1u)) >> 16;
}
__device__ __forceinline__ float bf16f(unsigned h) {
    return __builtin_bit_cast(float, h << 16);
}
__device__ __forceinline__ unsigned pk2(float a, float b) {
    return bf16_rne(a) | (bf16_rne(b) << 16);
}

// ---------------- kernel 1: per-block (64 rows) flash step via split-bf16 MFMA ----------------
__global__ __launch_bounds__(256) void bayes_k1(
    const float* __restrict__ inputs, const float* __restrict__ alphas,
    const float* __restrict__ data, float* __restrict__ ws)
{
    __shared__ __align__(16) char arena[ARENA];

    const int tid  = threadIdx.x;
    const int lane = tid & 63;
    const int wv   = tid >> 6;       // 0..3
    const int ln   = lane & 15;
    const int g    = lane >> 4;      // 0..3
    const int bid  = blockIdx.x;

    // ---- stage A: rows -> Rh/Rl (hi/lo split) + f32 norms. t: r=t>>2, 32-float chunk c4.
    {
        const int r = tid >> 2, c4 = tid & 3;
        const float4* gp = (const float4*)(data + ((size_t)bid * RPB + r) * DD + c4 * 32);
        float v[32];
        #pragma unroll
        for (int i = 0; i < 8; ++i) {
            const float4 t4 = gp[i];
            v[4*i+0] = t4.x; v[4*i+1] = t4.y; v[4*i+2] = t4.z; v[4*i+3] = t4.w;
        }
        float nn = 0.0f;
        #pragma unroll
        for (int i = 0; i < 32; ++i) nn = fmaf(v[i], v[i], nn);
        nn += __shfl_xor(nn, 1);
        nn += __shfl_xor(nn, 2);
        if (c4 == 0) *(float*)(arena + O_NRM + r * 4) = nn;

        const int swz = (r & 7) << 4;
        #pragma unroll
        for (int u = 0; u < 4; ++u) {       // 4 granules of 8 bf16
            unsigned hw[4], lw[4];
            #pragma unroll
            for (int j = 0; j < 4; ++j) {
                const float a = v[u*8 + 2*j], b = v[u*8 + 2*j + 1];
                const unsigned ah = bf16_rne(a), bh = bf16_rne(b);
                hw[j] = ah | (bh << 16);
                lw[j] = pk2(a - bf16f(ah), b - bf16f(bh));
            }
            const int go = (c4 * 64 + u * 16) ^ swz;
            *(uint4*)(arena + O_RH + r * 256 + go) = make_uint4(hw[0], hw[1], hw[2], hw[3]);
            *(uint4*)(arena + O_RL + r * 256 + go) = make_uint4(lw[0], lw[1], lw[2], lw[3]);
        }
    }

    // ---- stage A2: inputs -> inh/inl. t: b=t>>3, 16-float chunk c8.
    {
        const int b = tid >> 3, c8 = tid & 7;
        const float4* gp = (const float4*)(inputs + b * DD + c8 * 16);
        float v[16];
        #pragma unroll
        for (int i = 0; i < 4; ++i) {
            const float4 t4 = gp[i];
            v[4*i+0] = t4.x; v[4*i+1] = t4.y; v[4*i+2] = t4.z; v[4*i+3] = t4.w;
        }
        const int swz = (b & 7) << 4;
        #pragma unroll
        for (int u = 0; u < 2; ++u) {
            unsigned hw[4], lw[4];
            #pragma unroll
            for (int j = 0; j < 4; ++j) {
                const float a = v[u*8 + 2*j], bb = v[u*8 + 2*j + 1];
                const unsigned ah = bf16_rne(a), bh = bf16_rne(bb);
                hw[j] = ah | (bh << 16);
                lw[j] = pk2(a - bf16f(ah), bb - bf16f(bh));
            }
            const int go = (c8 * 32 + u * 16) ^ swz;
            *(uint4*)(arena + O_INH + b * 256 + go) = make_uint4(hw[0], hw[1], hw[2], hw[3]);
            *(uint4*)(arena + O_INL + b * 256 + go) = make_uint4(lw[0], lw[1], lw[2], lw[3]);
        }
    }

    // ---- stage B: transposed re-read (L2-hot) -> RT hi. t: d=t>>1, r-half rh.
    {
        const int d = tid >> 1, rh = tid & 1;
        const float* gc = data + ((size_t)bid * RPB + rh * 32) * DD + d;
        const int swz = (d & 7) << 4;
        #pragma unroll
        for (int u = 0; u < 4; ++u) {       // granule u: local rows u*8..u*8+7
            unsigned w[4];
            #pragma unroll
            for (int j = 0; j < 4; ++j)
                w[j] = pk2(gc[(u*8 + 2*j) * DD], gc[(u*8 + 2*j + 1) * DD]);
            *(uint4*)(arena + O_RT + d * 128 + ((rh * 64 + u * 16) ^ swz)) =
                make_uint4(w[0], w[1], w[2], w[3]);
        }
    }
    __syncthreads();

    // ---- GEMM-1: L[r,b] = rows · in^T, split-bf16 3-term, K-split across wave pairs
    const int ni = wv & 1;   // b-half
    const int kh = wv >> 1;  // k-half
    f32x4 acc1[4];
    #pragma unroll
    for (int mt = 0; mt < 4; ++mt)
        #pragma unroll
        for (int i = 0; i < 4; ++i) acc1[mt][i] = 0.0f;

    #pragma unroll
    for (int ks = 0; ks < 2; ++ks) {
        const int kbyte = kh * 128 + ks * 64 + g * 16;
        const int n = ni * 16 + ln;
        const bf16x8 Bh = *(const bf16x8*)(arena + O_INH + n * 256 + (kbyte ^ ((n & 7) << 4)));
        const bf16x8 Bl = *(const bf16x8*)(arena + O_INL + n * 256 + (kbyte ^ ((n & 7) << 4)));
        #pragma unroll
        for (int mt = 0; mt < 4; ++mt) {
            const int r = mt * 16 + ln;
            const bf16x8 Ah = *(const bf16x8*)(arena + O_RH + r * 256 + (kbyte ^ ((r & 7) << 4)));
            const bf16x8 Al = *(const bf16x8*)(arena + O_RL + r * 256 + (kbyte ^ ((r & 7) << 4)));
            acc1[mt] = __builtin_amdgcn_mfma_f32_16x16x32_bf16(Ah, Bh, acc1[mt], 0, 0, 0);
            acc1[mt] = __builtin_amdgcn_mfma_f32_16x16x32_bf16(Al, Bh, acc1[mt], 0, 0, 0);
            acc1[mt] = __builtin_amdgcn_mfma_f32_16x16x32_bf16(Ah, Bl, acc1[mt], 0, 0, 0);
        }
    }
    if (kh == 1) {
        #pragma unroll
        for (int mt = 0; mt < 4; ++mt)
            *(f32x4*)(arena + O_D1 + ((ni * 4 + mt) * 16 + ln) * 80 + g * 16) = acc1[mt];
    }
    __syncthreads();

    // ---- softmax (waves 0,1): merge k-halves, logits, max/exp/sum, P^T bf16, write m,s
    if (kh == 0) {
        const int b = ni * 16 + ln;
        #pragma unroll
        for (int mt = 0; mt < 4; ++mt) {
            const f32x4 o = *(const f32x4*)(arena + O_D1 + ((ni * 4 + mt) * 16 + ln) * 80 + g * 16);
            #pragma unroll
            for (int i = 0; i < 4; ++i) acc1[mt][i] += o[i];
        }
        const float alpha = alphas[b];
        const float var = 1.0f - alpha;
        const float c1 = sqrtf(alpha) / var;
        const float c2 = 0.5f * alpha / var;

        float lg[4][4];
        float mx = -1e30f;
        #pragma unroll
        for (int mt = 0; mt < 4; ++mt) {
            const f32x4 nr4 = *(const f32x4*)(arena + O_NRM + (mt * 16 + g * 4) * 4);
            #pragma unroll
            for (int i = 0; i < 4; ++i) {
                lg[mt][i] = fmaf(c1, acc1[mt][i], -c2 * nr4[i]);
                mx = fmaxf(mx, lg[mt][i]);
            }
        }
        mx = fmaxf(mx, __shfl_xor(mx, 16));
        mx = fmaxf(mx, __shfl_xor(mx, 32));

        float ss = 0.0f;
        const int swz = (b & 7) << 4;
        #pragma unroll
        for (int mt = 0; mt < 4; ++mt) {
            float e0 = __expf(lg[mt][0] - mx), e1 = __expf(lg[mt][1] - mx);
            float e2 = __expf(lg[mt][2] - mx), e3 = __expf(lg[mt][3] - mx);
            ss += (e0 + e1) + (e2 + e3);
            *(uint2*)(arena + O_PT + b * 128 + ((mt * 32 + g * 8) ^ swz)) =
                make_uint2(pk2(e0, e1), pk2(e2, e3));
        }
        ss += __shfl_xor(ss, 16);
        ss += __shfl_xor(ss, 32);
        if (g == 0) {
            float* wsp = ws + ((size_t)b * NB + bid) * WS_STRIDE;
            wsp[0] = mx; wsp[1] = ss;
        }
    }
    __syncthreads();

    // ---- PV: x0^T[d,b] = rows^T(hi) · P  (K = 64 rows, d split across 4 waves)
    {
        f32x4 acc2[2][2];
        #pragma unroll
        for (int a = 0; a < 2; ++a)
            #pragma unroll
            for (int c = 0; c < 2; ++c)
                #pragma unroll
                for (int i = 0; i < 4; ++i) acc2[a][c][i] = 0.0f;

        #pragma unroll
        for (int ks = 0; ks < 2; ++ks) {
            bf16x8 Bp[2];
            #pragma unroll
            for (int nt = 0; nt < 2; ++nt) {
                const int b2 = nt * 16 + ln;
                Bp[nt] = *(const bf16x8*)(arena + O_PT + b2 * 128 +
                                          ((ks * 64 + g * 16) ^ ((b2 & 7) << 4)));
            }
            #pragma unroll
            for (int mt2 = 0; mt2 < 2; ++mt2) {
                const int d = wv * 32 + mt2 * 16 + ln;
                const bf16x8 Ar = *(const bf16x8*)(arena + O_RT + d * 128 +
                                                   ((ks * 64 + g * 16) ^ ((d & 7) << 4)));
                #pragma unroll
                for (int nt = 0; nt < 2; ++nt)
                    acc2[mt2][nt] = __builtin_amdgcn_mfma_f32_16x16x32_bf16(Ar, Bp[nt], acc2[mt2][nt], 0, 0, 0);
            }
        }
        // x0 bounce -> LDS [b][d] f32 (overlays Rh; Rh dead since GEMM-1)
        #pragma unroll
        for (int mt2 = 0; mt2 < 2; ++mt2)
            #pragma unroll
            for (int nt = 0; nt < 2; ++nt) {
                const int b = nt * 16 + ln;
                const int d0 = wv * 32 + mt2 * 16 + g * 4;
                *(f32x4*)(arena + O_X0 + b * 512 + ((d0 * 4) ^ ((b & 7) << 4))) = acc2[mt2][nt];
            }
    }
    __syncthreads();

    // ---- coalesced partial write: ws[b][bid][4..132] = x0 row
    {
        const int b = tid >> 3, c8 = tid & 7;
        const int swz = (b & 7) << 4;
        float* dst = ws + ((size_t)b * NB + bid) * WS_STRIDE + 4 + c8 * 16;
        #pragma unroll
        for (int u = 0; u < 4; ++u) {
            const f32x4 v = *(const f32x4*)(arena + O_X0 + b * 512 + ((c8 * 64 + u * 16) ^ swz));
            *(f32x4*)(dst + u * 4) = v;
        }
    }
}

// ---------------- kernel 2: cross-block softmax combine + output (b-major ws) ----------------
__global__ __launch_bounds__(256) void bayes_k2(
    const float* __restrict__ inputs, const float* __restrict__ alphas,
    const float* __restrict__ ws, float* __restrict__ out)
{
    const int b   = blockIdx.x >> 2;   // 0..31
    const int dq  = blockIdx.x & 3;    // d-quarter
    const int tid = threadIdx.x;

    __shared__ float e_s[NP];
    __shared__ float red_s[16];
    __shared__ float part[8][32];

    const float* base_b = ws + (size_t)b * NP * WS_STRIDE;

    float mi[2], si[2];
    #pragma unroll
    for (int q = 0; q < 2; ++q) {
        const int i = tid + q * 256;
        mi[q] = base_b[(size_t)i * WS_STRIDE];
        si[q] = base_b[(size_t)i * WS_STRIDE + 1];
    }

    float mm = fmaxf(mi[0], mi[1]);
    #pragma unroll
    for (int off = 1; off <= 32; off <<= 1) mm = fmaxf(mm, __shfl_xor(mm, off));
    if ((tid & 63) == 0) red_s[tid >> 6] = mm;
    __syncthreads();
    const float M = fmaxf(fmaxf(red_s[0], red_s[1]), fmaxf(red_s[2], red_s[3]));

    float ss = 0.0f;
    #pragma unroll
    for (int q = 0; q < 2; ++q) {
        const float ei = __expf(mi[q] - M);
        e_s[tid + q * 256] = ei;
        ss = fmaf(si[q], ei, ss);
    }
    #pragma unroll
    for (int off = 1; off <= 32; off <<= 1) ss += __shfl_xor(ss, off);
    if ((tid & 63) == 0) red_s[8 + (tid >> 6)] = ss;
    __syncthreads();
    const float S = (red_s[8] + red_s[9]) + (red_s[10] + red_s[11]);

    // x0 slice: 32 d-values, 8-way split over 512 partials (64 each); contiguous region per b
    const int dd = tid & 31, ii = tid >> 5;
    const int d  = dq * 32 + dd;
    float x = 0.0f;
    #pragma unroll 8
    for (int k = 0; k < 64; ++k) {
        const int i = ii + k * 8;
        x = fmaf(e_s[i], base_b[(size_t)i * WS_STRIDE + 4 + d], x);
    }
    part[ii][dd] = x;
    __syncthreads();

    if (tid < 32) {
        float x0 = 0.0f;
        #pragma unroll
        for (int p = 0; p < 8; ++p) x0 += part[p][tid];
        x0 /= S;
        const float alpha = alphas[b];
        const float sa  = sqrtf(alpha);
        const float var = 1.0f - alpha;
        const int dout  = dq * 32 + tid;
        out[b * DD + dout] = (inputs[b * DD + dout] - sa * x0) / sqrtf(var);
    }
}

extern "C" void kernel_launch(void* const* d_in, const int* in_sizes, int n_in,
                              void* d_out, int out_size, void* d_ws, size_t ws_size,
                              hipStream_t stream)
{
    const float* inputs = (const float*)d_in[0];   // [B,D]
    const float* alphas = (const float*)d_in[1];   // [B]
    const float* data   = (const float*)d_in[2];   // [N,D]
    float* out = (float*)d_out;
    float* ws  = (float*)d_ws;                     // uses BB*NB*136*4 = 8.9 MB

    bayes_k1<<<NB, 256, 0, stream>>>(inputs, alphas, data, ws);
    bayes_k2<<<BB * 4, 256, 0, stream>>>(inputs, alphas, ws, out);
}